// Round 5
// baseline (121.719 us; speedup 1.0000x reference)
//
#include <hip/hip_runtime.h>

// SliceNApply: bilateral-grid trilinear slice + per-pixel 3x4 affine apply.
// FP32 tensors. B=4, C=12, D=8, Hg=Wg=16, H=W=1024.
//
// R11: resubmit of R10 (container acquisition failed twice; no signal).
//   Geometry re-verified by hand: fy0 uniform per 32-row tile, wyb
//   selects the half-cell offset; edge clamps match reference.
//
// R10: raise occupancy 16 -> 24 waves/CU.
//   Evidence: R9's ILP prefetch gained only -2.6us (pred -8..-14): kernel
//   ~33us vs overlapped floor ~20us; grid 1024 blocks = exactly 4
//   blocks/CU and launch_bounds(256,4) = 4 waves/SIMD (50% occ) -> the
//   guide->s->ds_read dependent chain can't be hidden by TLP.
//   Fix: (a) tile 64x64 -> 64x32: grid 2048 blocks = 8 blocks/CU of work;
//   a 32-row tile spans exactly 2 y-cell rows (fy0 uniform per tile), so
//   staging drops to 6 cells, ZSTRIDE 132->100 (still ==4 mod 32:
//   conflict-free 4s-bank spread), cof loses its by term.
//   (b) __launch_bounds__(256,6): VGPR cap ~84 (R6 scalar body = 84) ->
//   6 resident blocks/CU = 24 waves/CU. (c) iter-0 pixel loads issued
//   BEFORE the staging loop (hide HBM latency under stage+barrier).
//   Kept (verified R2-R9): f16 z-pair pack + v_dot2_f32_f16, 12
//   ds_read_b128/px, 2px/lane float2 I/O, 1-deep prefetch, all-scalar
//   compute (scratch-proof).

#define ZSTRIDE 100   // 6 cells * 12 ch = 72 dwords + 28 pad (100 % 32 == 4)

using half2v = decltype(__builtin_amdgcn_cvt_pkrtz(0.0f, 0.0f));

static __device__ __forceinline__ half2v pkrtz(float lo, float hi) {
    return __builtin_amdgcn_cvt_pkrtz(lo, hi);   // v_cvt_pkrtz_f16_f32
}
static __device__ __forceinline__ half2v u2h2(unsigned int u) {
    return __builtin_bit_cast(half2v, u);
}
static __device__ __forceinline__ unsigned int h2u(half2v h) {
    return __builtin_bit_cast(unsigned int, h);
}

#if __has_builtin(__builtin_amdgcn_fdot2)
#define DOT2(d, wp, acc) __builtin_amdgcn_fdot2(u2h2(d), (wp), (acc), false)
#else
static __device__ __forceinline__ float dot2_sw(unsigned int d, half2v wp, float acc) {
    half2v h = u2h2(d);
    return fmaf((float)wp.x, (float)h.x, fmaf((float)wp.y, (float)h.y, acc));
}
#define DOT2(d, wp, acc) dot2_sw((d), (wp), (acc))
#endif

// one corner's 4-channel dual-z dot-accumulate (all scalar refs)
static __device__ __forceinline__ void corner_dot(
    const unsigned int* __restrict__ cp, half2v wp,
    float& a0, float& a1, float& a2, float& a3)
{
    const uint4 d = *reinterpret_cast<const uint4*>(cp);
    a0 = DOT2(d.x, wp, a0);
    a1 = DOT2(d.y, wp, a1);
    a2 = DOT2(d.z, wp, a2);
    a3 = DOT2(d.w, wp, a3);
}

// full per-pixel slice + apply; everything scalar (scratch-proof)
static __device__ __forceinline__ void px_eval(
    const unsigned int* __restrict__ lds,
    float g, float f0, float f1, float f2,
    float u0, float u1, float v0, float v1,
    int cof0, int cof1, int cof2, int cof3,
    float& o0, float& o1, float& o2)
{
    const float gz = g * 8.0f - 0.5f;
    int s = (int)floorf(gz);
    s = min(max(s, 0), 7);
    const float wz = fmaxf(gz - (float)s, 0.0f);
    const float zl = 1.0f - wz, zh = wz;
    const unsigned int* sb = &lds[s * ZSTRIDE];

    const float w00 = v0 * u0, w01 = v0 * u1;
    const float w10 = v1 * u0, w11 = v1 * u1;
    const half2v wp0 = pkrtz(w00 * zl, w00 * zh);
    const half2v wp1 = pkrtz(w01 * zl, w01 * zh);
    const half2v wp2 = pkrtz(w10 * zl, w10 * zh);
    const half2v wp3 = pkrtz(w11 * zl, w11 * zh);

    {
        float a0 = 0.f, a1 = 0.f, a2 = 0.f, a3 = 0.f;
        corner_dot(sb + cof0, wp0, a0, a1, a2, a3);
        corner_dot(sb + cof1, wp1, a0, a1, a2, a3);
        corner_dot(sb + cof2, wp2, a0, a1, a2, a3);
        corner_dot(sb + cof3, wp3, a0, a1, a2, a3);
        o0 = fmaf(a0, f0, fmaf(a1, f1, fmaf(a2, f2, a3)));
    }
    {
        float a0 = 0.f, a1 = 0.f, a2 = 0.f, a3 = 0.f;
        corner_dot(sb + cof0 + 4, wp0, a0, a1, a2, a3);
        corner_dot(sb + cof1 + 4, wp1, a0, a1, a2, a3);
        corner_dot(sb + cof2 + 4, wp2, a0, a1, a2, a3);
        corner_dot(sb + cof3 + 4, wp3, a0, a1, a2, a3);
        o1 = fmaf(a0, f0, fmaf(a1, f1, fmaf(a2, f2, a3)));
    }
    {
        float a0 = 0.f, a1 = 0.f, a2 = 0.f, a3 = 0.f;
        corner_dot(sb + cof0 + 8, wp0, a0, a1, a2, a3);
        corner_dot(sb + cof1 + 8, wp1, a0, a1, a2, a3);
        corner_dot(sb + cof2 + 8, wp2, a0, a1, a2, a3);
        corner_dot(sb + cof3 + 8, wp3, a0, a1, a2, a3);
        o2 = fmaf(a0, f0, fmaf(a1, f1, fmaf(a2, f2, a3)));
    }
}

__global__ __launch_bounds__(256, 6) void slice_apply(
    const float* __restrict__ grid,   // [4][12][8][16][16]
    const float* __restrict__ guide,  // [4][1][1024][1024]
    const float* __restrict__ fr,     // [4][3][1024][1024]
    float* __restrict__ out)          // [4][3][1024][1024]
{
    __shared__ __align__(16) unsigned int lds[8 * ZSTRIDE];

    const int b     = blockIdx.y;
    const int tileX = blockIdx.x & 15;   // 0..15  (64-px columns)
    const int tileY = blockIdx.x >> 4;   // 0..31  (32-px rows)
    const int t     = threadIdx.x;

    // wave = quadrant (32x16 px); lane -> 2 adjacent-x px:
    //   16 x-pairs (float2), 4 sub-rows per iter, 4 iters.
    const int w   = t >> 6;
    const int l   = t & 63;
    const int by  = w >> 1;          // wave-uniform (row half)
    const int bx  = w & 1;           // wave-uniform (col half)
    const int lx2 = l & 15;          // x-pair index within quadrant
    const int sub = l >> 4;          // sub-row 0..3

    const int txA = bx * 32 + lx2 * 2;                  // tile-local x of px A
    const int xg  = tileX * 64 + txA;                   // global x (even)
    const int y0  = tileY * 32 + by * 16 + sub;         // iter-0 global y
    int gofs = (b * 1024 + y0) * 1024 + xg;
    int fofs = ((b * 3) * 1024 + y0) * 1024 + xg;

    // ---- prologue pixel loads BEFORE staging: HBM latency hides under
    //      the LDS fill + barrier ----
    float2 gv  = *reinterpret_cast<const float2*>(guide + gofs);
    float2 f0v = *reinterpret_cast<const float2*>(fr + fofs);
    float2 f1v = *reinterpret_cast<const float2*>(fr + fofs + 1048576);
    float2 f2v = *reinterpret_cast<const float2*>(fr + fofs + 2097152);

    // ---- stage 2x3-cell grid slice into LDS, z-pair packed as f16x2 ----
    {
        const int yodd = tileY & 1;
        const int fy0  = (tileY >> 1) - 1 + yodd;       // uniform per tile
        const int ry0  = min(max(fy0, 0), 15);
        const int ry1  = min(max(fy0 + 1, 0), 15);
        const int px0  = min(max(tileX - 1, 0), 15);
        const int px1  = tileX;
        const int px2  = min(tileX + 1, 15);
        for (int e = t; e < 8 * 6 * 12; e += 256) {
            const int c    = e % 12;
            const int cell = (e / 12) % 6;
            const int s    = e / 72;
            const int s2   = min(s + 1, 7);
            const int yr   = cell / 3;   // 0,1
            const int xc   = cell % 3;
            const int ry = yr ? ry1 : ry0;
            const int rx = (xc == 0) ? px0 : ((xc == 1) ? px1 : px2);
            const int cb = (b * 12 + c) * 8;
            const int sp = ry * 16 + rx;
            const float lo = grid[(cb + s)  * 256 + sp];
            const float hi = grid[(cb + s2) * 256 + sp];
            lds[s * ZSTRIDE + cell * 12 + c] = h2u(pkrtz(lo, hi));
        }
    }
    __syncthreads();

    const float wxA = ((float)txA + 0.5f) * 0.015625f + (0.5f - (float)bx);
    const float wxB = wxA + 0.015625f;
    const float u1A = wxA, u0A = 1.0f - wxA;
    const float u1B = wxB, u0B = 1.0f - wxB;

    // corner dword offsets (both y-cell rows shared by whole tile)
    const int cof0 = (0 + bx) * 12;      // (yrow0, xcol bx)
    const int cof1 = (1 + bx) * 12;      // (yrow0, xcol bx+1)
    const int cof2 = (3 + bx) * 12;      // (yrow1, xcol bx)
    const int cof3 = (4 + bx) * 12;      // (yrow1, xcol bx+1)

    const float wyb = (tileY & 1) ? 0.0f : 0.5f;

    #pragma unroll
    for (int i = 0; i < 4; ++i) {
        // ---- issue next iteration's loads first (latency hiding) ----
        float2 gn = gv, f0n = f0v, f1n = f1v, f2n = f2v;
        if (i < 3) {
            const int gofs_n = gofs + 4 * 1024;   // +4 rows
            const int fofs_n = fofs + 4 * 1024;
            gn  = *reinterpret_cast<const float2*>(guide + gofs_n);
            f0n = *reinterpret_cast<const float2*>(fr + fofs_n);
            f1n = *reinterpret_cast<const float2*>(fr + fofs_n + 1048576);
            f2n = *reinterpret_cast<const float2*>(fr + fofs_n + 2097152);
        }

        // ---- compute current iteration ----
        const int ly = by * 16 + i * 4 + sub;     // tile-local y (0..31)
        const float wy = ((float)ly + 0.5f) * 0.015625f + wyb;
        const float v1 = wy, v0 = 1.0f - wy;

        float oA0, oA1, oA2, oB0, oB1, oB2;
        px_eval(lds, gv.x, f0v.x, f1v.x, f2v.x, u0A, u1A, v0, v1,
                cof0, cof1, cof2, cof3, oA0, oA1, oA2);
        px_eval(lds, gv.y, f0v.y, f1v.y, f2v.y, u0B, u1B, v0, v1,
                cof0, cof1, cof2, cof3, oB0, oB1, oB2);

        *reinterpret_cast<float2*>(out + fofs)           = make_float2(oA0, oB0);
        *reinterpret_cast<float2*>(out + fofs + 1048576) = make_float2(oA1, oB1);
        *reinterpret_cast<float2*>(out + fofs + 2097152) = make_float2(oA2, oB2);

        // ---- rotate ----
        gofs += 4 * 1024;
        fofs += 4 * 1024;
        gv = gn; f0v = f0n; f1v = f1n; f2v = f2n;
    }
}

extern "C" void kernel_launch(void* const* d_in, const int* in_sizes, int n_in,
                              void* d_out, int out_size, void* d_ws, size_t ws_size,
                              hipStream_t stream) {
    const float* grid  = (const float*)d_in[0];
    const float* guide = (const float*)d_in[1];
    const float* fr    = (const float*)d_in[2];
    float* out = (float*)d_out;

    dim3 g(512, 4);   // 16x32 tiles of 64x32 px, 4 batches
    dim3 blk(256);
    hipLaunchKernelGGL(slice_apply, g, blk, 0, stream, grid, guide, fr, out);
}

// Round 6
// 120.716 us; speedup vs baseline: 1.0083x; 1.0083x over previous
//
#include <hip/hip_runtime.h>

// SliceNApply: bilateral-grid trilinear slice + per-pixel 3x4 affine apply.
// FP32 tensors. B=4, C=12, D=8, Hg=Wg=16, H=W=1024.
//
// R12: single-variable fix of R11's regression: launch_bounds 6 -> 5.
//   Post-mortem R11 (121.7 vs R9 117.5, pred ~110): (256,6) caps VGPR at
//   ~85; body needs ~100-110 (R6 scalar=84 + 16 prefetch VGPRs + 2nd px
//   state) -> spill-to-scratch per iteration swamped the occupancy gain.
//   (256,5) caps at ~102: fits, still 5 blocks/CU = 20 waves/CU (vs R9's
//   grid-capped 16). Everything else identical to R11.
//   If this also regresses vs R9 -> per-block overhead theory, revert tile.
//
// R10/R11: 64x32 tile (2048 blocks = 8 blocks/CU of work), 6-cell staging
//   (fy0 uniform per 32-row tile), ZSTRIDE 100 (==4 mod 32, conflict-free),
//   iter-0 pixel loads before staging.
//   Kept (verified R2-R9): f16 z-pair pack + v_dot2_f32_f16, 12
//   ds_read_b128/px, 2px/lane float2 I/O, 1-deep prefetch, all-scalar
//   compute (scratch-proof).

#define ZSTRIDE 100   // 6 cells * 12 ch = 72 dwords + 28 pad (100 % 32 == 4)

using half2v = decltype(__builtin_amdgcn_cvt_pkrtz(0.0f, 0.0f));

static __device__ __forceinline__ half2v pkrtz(float lo, float hi) {
    return __builtin_amdgcn_cvt_pkrtz(lo, hi);   // v_cvt_pkrtz_f16_f32
}
static __device__ __forceinline__ half2v u2h2(unsigned int u) {
    return __builtin_bit_cast(half2v, u);
}
static __device__ __forceinline__ unsigned int h2u(half2v h) {
    return __builtin_bit_cast(unsigned int, h);
}

#if __has_builtin(__builtin_amdgcn_fdot2)
#define DOT2(d, wp, acc) __builtin_amdgcn_fdot2(u2h2(d), (wp), (acc), false)
#else
static __device__ __forceinline__ float dot2_sw(unsigned int d, half2v wp, float acc) {
    half2v h = u2h2(d);
    return fmaf((float)wp.x, (float)h.x, fmaf((float)wp.y, (float)h.y, acc));
}
#define DOT2(d, wp, acc) dot2_sw((d), (wp), (acc))
#endif

// one corner's 4-channel dual-z dot-accumulate (all scalar refs)
static __device__ __forceinline__ void corner_dot(
    const unsigned int* __restrict__ cp, half2v wp,
    float& a0, float& a1, float& a2, float& a3)
{
    const uint4 d = *reinterpret_cast<const uint4*>(cp);
    a0 = DOT2(d.x, wp, a0);
    a1 = DOT2(d.y, wp, a1);
    a2 = DOT2(d.z, wp, a2);
    a3 = DOT2(d.w, wp, a3);
}

// full per-pixel slice + apply; everything scalar (scratch-proof)
static __device__ __forceinline__ void px_eval(
    const unsigned int* __restrict__ lds,
    float g, float f0, float f1, float f2,
    float u0, float u1, float v0, float v1,
    int cof0, int cof1, int cof2, int cof3,
    float& o0, float& o1, float& o2)
{
    const float gz = g * 8.0f - 0.5f;
    int s = (int)floorf(gz);
    s = min(max(s, 0), 7);
    const float wz = fmaxf(gz - (float)s, 0.0f);
    const float zl = 1.0f - wz, zh = wz;
    const unsigned int* sb = &lds[s * ZSTRIDE];

    const float w00 = v0 * u0, w01 = v0 * u1;
    const float w10 = v1 * u0, w11 = v1 * u1;
    const half2v wp0 = pkrtz(w00 * zl, w00 * zh);
    const half2v wp1 = pkrtz(w01 * zl, w01 * zh);
    const half2v wp2 = pkrtz(w10 * zl, w10 * zh);
    const half2v wp3 = pkrtz(w11 * zl, w11 * zh);

    {
        float a0 = 0.f, a1 = 0.f, a2 = 0.f, a3 = 0.f;
        corner_dot(sb + cof0, wp0, a0, a1, a2, a3);
        corner_dot(sb + cof1, wp1, a0, a1, a2, a3);
        corner_dot(sb + cof2, wp2, a0, a1, a2, a3);
        corner_dot(sb + cof3, wp3, a0, a1, a2, a3);
        o0 = fmaf(a0, f0, fmaf(a1, f1, fmaf(a2, f2, a3)));
    }
    {
        float a0 = 0.f, a1 = 0.f, a2 = 0.f, a3 = 0.f;
        corner_dot(sb + cof0 + 4, wp0, a0, a1, a2, a3);
        corner_dot(sb + cof1 + 4, wp1, a0, a1, a2, a3);
        corner_dot(sb + cof2 + 4, wp2, a0, a1, a2, a3);
        corner_dot(sb + cof3 + 4, wp3, a0, a1, a2, a3);
        o1 = fmaf(a0, f0, fmaf(a1, f1, fmaf(a2, f2, a3)));
    }
    {
        float a0 = 0.f, a1 = 0.f, a2 = 0.f, a3 = 0.f;
        corner_dot(sb + cof0 + 8, wp0, a0, a1, a2, a3);
        corner_dot(sb + cof1 + 8, wp1, a0, a1, a2, a3);
        corner_dot(sb + cof2 + 8, wp2, a0, a1, a2, a3);
        corner_dot(sb + cof3 + 8, wp3, a0, a1, a2, a3);
        o2 = fmaf(a0, f0, fmaf(a1, f1, fmaf(a2, f2, a3)));
    }
}

__global__ __launch_bounds__(256, 5) void slice_apply(
    const float* __restrict__ grid,   // [4][12][8][16][16]
    const float* __restrict__ guide,  // [4][1][1024][1024]
    const float* __restrict__ fr,     // [4][3][1024][1024]
    float* __restrict__ out)          // [4][3][1024][1024]
{
    __shared__ __align__(16) unsigned int lds[8 * ZSTRIDE];

    const int b     = blockIdx.y;
    const int tileX = blockIdx.x & 15;   // 0..15  (64-px columns)
    const int tileY = blockIdx.x >> 4;   // 0..31  (32-px rows)
    const int t     = threadIdx.x;

    // wave = quadrant (32x16 px); lane -> 2 adjacent-x px:
    //   16 x-pairs (float2), 4 sub-rows per iter, 4 iters.
    const int w   = t >> 6;
    const int l   = t & 63;
    const int by  = w >> 1;          // wave-uniform (row half)
    const int bx  = w & 1;           // wave-uniform (col half)
    const int lx2 = l & 15;          // x-pair index within quadrant
    const int sub = l >> 4;          // sub-row 0..3

    const int txA = bx * 32 + lx2 * 2;                  // tile-local x of px A
    const int xg  = tileX * 64 + txA;                   // global x (even)
    const int y0  = tileY * 32 + by * 16 + sub;         // iter-0 global y
    int gofs = (b * 1024 + y0) * 1024 + xg;
    int fofs = ((b * 3) * 1024 + y0) * 1024 + xg;

    // ---- prologue pixel loads BEFORE staging: HBM latency hides under
    //      the LDS fill + barrier ----
    float2 gv  = *reinterpret_cast<const float2*>(guide + gofs);
    float2 f0v = *reinterpret_cast<const float2*>(fr + fofs);
    float2 f1v = *reinterpret_cast<const float2*>(fr + fofs + 1048576);
    float2 f2v = *reinterpret_cast<const float2*>(fr + fofs + 2097152);

    // ---- stage 2x3-cell grid slice into LDS, z-pair packed as f16x2 ----
    {
        const int yodd = tileY & 1;
        const int fy0  = (tileY >> 1) - 1 + yodd;       // uniform per tile
        const int ry0  = min(max(fy0, 0), 15);
        const int ry1  = min(max(fy0 + 1, 0), 15);
        const int px0  = min(max(tileX - 1, 0), 15);
        const int px1  = tileX;
        const int px2  = min(tileX + 1, 15);
        for (int e = t; e < 8 * 6 * 12; e += 256) {
            const int c    = e % 12;
            const int cell = (e / 12) % 6;
            const int s    = e / 72;
            const int s2   = min(s + 1, 7);
            const int yr   = cell / 3;   // 0,1
            const int xc   = cell % 3;
            const int ry = yr ? ry1 : ry0;
            const int rx = (xc == 0) ? px0 : ((xc == 1) ? px1 : px2);
            const int cb = (b * 12 + c) * 8;
            const int sp = ry * 16 + rx;
            const float lo = grid[(cb + s)  * 256 + sp];
            const float hi = grid[(cb + s2) * 256 + sp];
            lds[s * ZSTRIDE + cell * 12 + c] = h2u(pkrtz(lo, hi));
        }
    }
    __syncthreads();

    const float wxA = ((float)txA + 0.5f) * 0.015625f + (0.5f - (float)bx);
    const float wxB = wxA + 0.015625f;
    const float u1A = wxA, u0A = 1.0f - wxA;
    const float u1B = wxB, u0B = 1.0f - wxB;

    // corner dword offsets (both y-cell rows shared by whole tile)
    const int cof0 = (0 + bx) * 12;      // (yrow0, xcol bx)
    const int cof1 = (1 + bx) * 12;      // (yrow0, xcol bx+1)
    const int cof2 = (3 + bx) * 12;      // (yrow1, xcol bx)
    const int cof3 = (4 + bx) * 12;      // (yrow1, xcol bx+1)

    const float wyb = (tileY & 1) ? 0.0f : 0.5f;

    #pragma unroll
    for (int i = 0; i < 4; ++i) {
        // ---- issue next iteration's loads first (latency hiding) ----
        float2 gn = gv, f0n = f0v, f1n = f1v, f2n = f2v;
        if (i < 3) {
            const int gofs_n = gofs + 4 * 1024;   // +4 rows
            const int fofs_n = fofs + 4 * 1024;
            gn  = *reinterpret_cast<const float2*>(guide + gofs_n);
            f0n = *reinterpret_cast<const float2*>(fr + fofs_n);
            f1n = *reinterpret_cast<const float2*>(fr + fofs_n + 1048576);
            f2n = *reinterpret_cast<const float2*>(fr + fofs_n + 2097152);
        }

        // ---- compute current iteration ----
        const int ly = by * 16 + i * 4 + sub;     // tile-local y (0..31)
        const float wy = ((float)ly + 0.5f) * 0.015625f + wyb;
        const float v1 = wy, v0 = 1.0f - wy;

        float oA0, oA1, oA2, oB0, oB1, oB2;
        px_eval(lds, gv.x, f0v.x, f1v.x, f2v.x, u0A, u1A, v0, v1,
                cof0, cof1, cof2, cof3, oA0, oA1, oA2);
        px_eval(lds, gv.y, f0v.y, f1v.y, f2v.y, u0B, u1B, v0, v1,
                cof0, cof1, cof2, cof3, oB0, oB1, oB2);

        *reinterpret_cast<float2*>(out + fofs)           = make_float2(oA0, oB0);
        *reinterpret_cast<float2*>(out + fofs + 1048576) = make_float2(oA1, oB1);
        *reinterpret_cast<float2*>(out + fofs + 2097152) = make_float2(oA2, oB2);

        // ---- rotate ----
        gofs += 4 * 1024;
        fofs += 4 * 1024;
        gv = gn; f0v = f0n; f1v = f1n; f2v = f2n;
    }
}

extern "C" void kernel_launch(void* const* d_in, const int* in_sizes, int n_in,
                              void* d_out, int out_size, void* d_ws, size_t ws_size,
                              hipStream_t stream) {
    const float* grid  = (const float*)d_in[0];
    const float* guide = (const float*)d_in[1];
    const float* fr    = (const float*)d_in[2];
    float* out = (float*)d_out;

    dim3 g(512, 4);   // 16x32 tiles of 64x32 px, 4 batches
    dim3 blk(256);
    hipLaunchKernelGGL(slice_apply, g, blk, 0, stream, grid, guide, fr, out);
}

// Round 7
// 119.402 us; speedup vs baseline: 1.0194x; 1.0110x over previous
//
#include <hip/hip_runtime.h>

// SliceNApply: bilateral-grid trilinear slice + per-pixel 3x4 affine apply.
// FP32 tensors. B=4, C=12, D=8, Hg=Wg=16, H=W=1024.
//
// R13: cross the 64-VGPR occupancy cliff -> 8 waves/SIMD.
//   Post-mortem R11/R12: occupancy steps at VGPR 64/128/256 (8/4/2
//   waves/SIMD, pool=512/SIMD). R9(~100)/R11(cap85)/R12(cap102) all sat
//   in the SAME 4-wave band -> tile split was pure overhead (+3us).
//   Meanwhile kernel ~33.5us == LDS pipe (15.4us, 3072 ds_read_b128/CU)
//   + HBM (18.6us) SERIAL -> at 4 waves/SIMD, lgkmcnt stalls leave VMEM
//   idle. Fix: VGPR <= 64 => 32 waves/CU, 2x TLP:
//   1 px/lane, NO software prefetch (8-wave TLP covers ~900cyc HBM
//   latency: 8 waves x ~160 VALU cyc/iter = 1300cyc), #pragma unroll 1
//   (compact body, no unroller pressure), launch_bounds(256,8),
//   64x32 tile (2048 blocks = 8 blocks/CU of work).
//   If FETCH/WRITE inflate + dur regresses -> forced spills -> revert R9.
//   Kept (verified R2-R12): f16 z-pair pack + v_dot2_f32_f16, 12
//   ds_read_b128/px, 6-cell staging (fy0 uniform per 32-row tile),
//   ZSTRIDE 100 (==4 mod 32, conflict-free), all-scalar compute.

#define ZSTRIDE 100   // 6 cells * 12 ch = 72 dwords + 28 pad (100 % 32 == 4)

using half2v = decltype(__builtin_amdgcn_cvt_pkrtz(0.0f, 0.0f));

static __device__ __forceinline__ half2v pkrtz(float lo, float hi) {
    return __builtin_amdgcn_cvt_pkrtz(lo, hi);   // v_cvt_pkrtz_f16_f32
}
static __device__ __forceinline__ half2v u2h2(unsigned int u) {
    return __builtin_bit_cast(half2v, u);
}
static __device__ __forceinline__ unsigned int h2u(half2v h) {
    return __builtin_bit_cast(unsigned int, h);
}

#if __has_builtin(__builtin_amdgcn_fdot2)
#define DOT2(d, wp, acc) __builtin_amdgcn_fdot2(u2h2(d), (wp), (acc), false)
#else
static __device__ __forceinline__ float dot2_sw(unsigned int d, half2v wp, float acc) {
    half2v h = u2h2(d);
    return fmaf((float)wp.x, (float)h.x, fmaf((float)wp.y, (float)h.y, acc));
}
#define DOT2(d, wp, acc) dot2_sw((d), (wp), (acc))
#endif

// one corner's 4-channel dual-z dot-accumulate (all scalar refs)
static __device__ __forceinline__ void corner_dot(
    const unsigned int* __restrict__ cp, half2v wp,
    float& a0, float& a1, float& a2, float& a3)
{
    const uint4 d = *reinterpret_cast<const uint4*>(cp);
    a0 = DOT2(d.x, wp, a0);
    a1 = DOT2(d.y, wp, a1);
    a2 = DOT2(d.z, wp, a2);
    a3 = DOT2(d.w, wp, a3);
}

__global__ __launch_bounds__(256, 8) void slice_apply(
    const float* __restrict__ grid,   // [4][12][8][16][16]
    const float* __restrict__ guide,  // [4][1][1024][1024]
    const float* __restrict__ fr,     // [4][3][1024][1024]
    float* __restrict__ out)          // [4][3][1024][1024]
{
    __shared__ __align__(16) unsigned int lds[8 * ZSTRIDE];

    const int b     = blockIdx.y;
    const int tileX = blockIdx.x & 15;   // 0..15  (64-px columns)
    const int tileY = blockIdx.x >> 4;   // 0..31  (32-px rows)
    const int t     = threadIdx.x;

    // ---- stage 2x3-cell grid slice into LDS, z-pair packed as f16x2 ----
    {
        const int yodd = tileY & 1;
        const int fy0  = (tileY >> 1) - 1 + yodd;       // uniform per tile
        const int ry0  = min(max(fy0, 0), 15);
        const int ry1  = min(max(fy0 + 1, 0), 15);
        const int px0  = min(max(tileX - 1, 0), 15);
        const int px1  = tileX;
        const int px2  = min(tileX + 1, 15);
        for (int e = t; e < 8 * 6 * 12; e += 256) {
            const int c    = e % 12;
            const int cell = (e / 12) % 6;
            const int s    = e / 72;
            const int s2   = min(s + 1, 7);
            const int yr   = cell / 3;   // 0,1
            const int xc   = cell % 3;
            const int ry = yr ? ry1 : ry0;
            const int rx = (xc == 0) ? px0 : ((xc == 1) ? px1 : px2);
            const int cb = (b * 12 + c) * 8;
            const int sp = ry * 16 + rx;
            const float lo = grid[(cb + s)  * 256 + sp];
            const float hi = grid[(cb + s2) * 256 + sp];
            lds[s * ZSTRIDE + cell * 12 + c] = h2u(pkrtz(lo, hi));
        }
    }
    __syncthreads();

    // wave = quadrant (32x16 px); lane -> 1 px: 32 x-lanes, 2 sub-rows,
    // 8 iterations of 2 rows each.
    const int w   = t >> 6;
    const int l   = t & 63;
    const int by  = w >> 1;          // wave-uniform (row half)
    const int bx  = w & 1;           // wave-uniform (col half)
    const int lx  = l & 31;          // x within quadrant
    const int sub = l >> 5;          // sub-row 0..1

    const int tx  = bx * 32 + lx;                       // tile-local x
    const int xg  = tileX * 64 + tx;                    // global x
    const int y0  = tileY * 32 + by * 16 + sub;         // iter-0 global y
    int gofs = (b * 1024 + y0) * 1024 + xg;
    int fofs = ((b * 3) * 1024 + y0) * 1024 + xg;

    const float wx = ((float)tx + 0.5f) * 0.015625f + (0.5f - (float)bx);
    const float u1 = wx, u0 = 1.0f - wx;

    // corner dword offsets (both y-cell rows shared by whole tile)
    const int cof0 = (0 + bx) * 12;      // (yrow0, xcol bx)
    const int cof1 = (1 + bx) * 12;      // (yrow0, xcol bx+1)
    const int cof2 = (3 + bx) * 12;      // (yrow1, xcol bx)
    const int cof3 = (4 + bx) * 12;      // (yrow1, xcol bx+1)

    const float wyb = (tileY & 1) ? 0.0f : 0.5f;

    #pragma unroll 1
    for (int i = 0; i < 8; ++i) {
        const float g  = guide[gofs];
        const float f0 = fr[fofs];
        const float f1 = fr[fofs + 1048576];
        const float f2 = fr[fofs + 2097152];

        const int ly = by * 16 + i * 2 + sub;     // tile-local y (0..31)
        const float wy = ((float)ly + 0.5f) * 0.015625f + wyb;
        const float v1 = wy, v0 = 1.0f - wy;

        const float gz = g * 8.0f - 0.5f;
        int s = (int)floorf(gz);
        s = min(max(s, 0), 7);
        const float wz = fmaxf(gz - (float)s, 0.0f);
        const float zl = 1.0f - wz, zh = wz;
        const unsigned int* sb = &lds[s * ZSTRIDE];

        const float w00 = v0 * u0, w01 = v0 * u1;
        const float w10 = v1 * u0, w11 = v1 * u1;
        const half2v wp0 = pkrtz(w00 * zl, w00 * zh);
        const half2v wp1 = pkrtz(w01 * zl, w01 * zh);
        const half2v wp2 = pkrtz(w10 * zl, w10 * zh);
        const half2v wp3 = pkrtz(w11 * zl, w11 * zh);

        float o0, o1, o2;
        {
            float a0 = 0.f, a1 = 0.f, a2 = 0.f, a3 = 0.f;
            corner_dot(sb + cof0, wp0, a0, a1, a2, a3);
            corner_dot(sb + cof1, wp1, a0, a1, a2, a3);
            corner_dot(sb + cof2, wp2, a0, a1, a2, a3);
            corner_dot(sb + cof3, wp3, a0, a1, a2, a3);
            o0 = fmaf(a0, f0, fmaf(a1, f1, fmaf(a2, f2, a3)));
        }
        {
            float a0 = 0.f, a1 = 0.f, a2 = 0.f, a3 = 0.f;
            corner_dot(sb + cof0 + 4, wp0, a0, a1, a2, a3);
            corner_dot(sb + cof1 + 4, wp1, a0, a1, a2, a3);
            corner_dot(sb + cof2 + 4, wp2, a0, a1, a2, a3);
            corner_dot(sb + cof3 + 4, wp3, a0, a1, a2, a3);
            o1 = fmaf(a0, f0, fmaf(a1, f1, fmaf(a2, f2, a3)));
        }
        {
            float a0 = 0.f, a1 = 0.f, a2 = 0.f, a3 = 0.f;
            corner_dot(sb + cof0 + 8, wp0, a0, a1, a2, a3);
            corner_dot(sb + cof1 + 8, wp1, a0, a1, a2, a3);
            corner_dot(sb + cof2 + 8, wp2, a0, a1, a2, a3);
            corner_dot(sb + cof3 + 8, wp3, a0, a1, a2, a3);
            o2 = fmaf(a0, f0, fmaf(a1, f1, fmaf(a2, f2, a3)));
        }

        out[fofs]           = o0;
        out[fofs + 1048576] = o1;
        out[fofs + 2097152] = o2;

        gofs += 2 * 1024;   // 2 rows per iteration
        fofs += 2 * 1024;
    }
}

extern "C" void kernel_launch(void* const* d_in, const int* in_sizes, int n_in,
                              void* d_out, int out_size, void* d_ws, size_t ws_size,
                              hipStream_t stream) {
    const float* grid  = (const float*)d_in[0];
    const float* guide = (const float*)d_in[1];
    const float* fr    = (const float*)d_in[2];
    float* out = (float*)d_out;

    dim3 g(512, 4);   // 16x32 tiles of 64x32 px, 4 batches
    dim3 blk(256);
    hipLaunchKernelGGL(slice_apply, g, blk, 0, stream, grid, guide, fr, out);
}